// Round 2
// baseline (426.399 us; speedup 1.0000x reference)
//
#include <hip/hip_runtime.h>

#define EMB_STRIDE 393216  // 96*64*64 floats per sample

// ---------------- Kernel 0: transpose in_proj_w [288][96] -> Wt [96][288] ----
__global__ __launch_bounds__(256) void k_transpose(const float* __restrict__ w_in,
                                                   float* __restrict__ wt) {
    int idx = blockIdx.x * 256 + threadIdx.x;
    if (idx < 96 * 288) {
        int e = idx / 288, f = idx % 288;
        wt[idx] = w_in[f * 96 + e];
    }
}

// ---------------- Kernel 1: patch merge (RAW reshape semantics) + 48->96 linear
// patches[n, k=c*16+j, o] = x[n, c, j*16 + a*4 + d, b*16 + cc*4 + g]
//   where o = a*1024 + b*64 + cc*16 + d*4 + g  (o = hp'*64+wp' in [0,4096))
// block = (n, a, eq); thread t in [0,1024) owns o_low = t; e in [eq*24, eq*24+24)
__global__ __launch_bounds__(1024) void k_patch_linear(const float* __restrict__ x,
                                                       const float* __restrict__ lin_w,
                                                       const float* __restrict__ lin_b,
                                                       float* __restrict__ emb) {
    const int bid = blockIdx.x;
    const int n  = bid >> 4;
    const int a  = (bid >> 2) & 3;
    const int eq = bid & 3;
    const int t  = threadIdx.x;

    __shared__ float lw[24 * 48];
    __shared__ float lb[24];
    for (int i = t; i < 24 * 48; i += 1024) lw[i] = lin_w[eq * 24 * 48 + i];
    if (t < 24) lb[t] = lin_b[eq * 24 + t];
    __syncthreads();

    const int b  = t >> 6;
    const int cc = (t >> 4) & 3;
    const int d  = (t >> 2) & 3;
    const int g  = t & 3;
    const int col  = b * 16 + cc * 4 + g;
    const int row0 = a * 4 + d;

    float xv[48];
    const float* xb = x + (size_t)n * 3 * 65536;
#pragma unroll
    for (int c = 0; c < 3; ++c)
#pragma unroll
        for (int j = 0; j < 16; ++j)
            xv[c * 16 + j] = xb[(size_t)(c * 256 + j * 16 + row0) * 256 + col];

    float* ebase = emb + (size_t)n * EMB_STRIDE + a * 1024 + t;
    for (int ei = 0; ei < 24; ++ei) {
        const float* wr = &lw[ei * 48];
        float acc = lb[ei];
#pragma unroll
        for (int k = 0; k < 48; k += 4) {
            acc += xv[k]     * wr[k]     + xv[k + 1] * wr[k + 1]
                 + xv[k + 2] * wr[k + 2] + xv[k + 3] * wr[k + 3];
        }
        ebase[(size_t)(eq * 24 + ei) * 4096] = acc;
    }
}

// ---------------- Kernel 2: fused window-MSA per (w, l) ---------------------
// X[n][e] = emb_flat[n][w*98304 + l*96 + e]  (16 x 96)  [raw reshape, faithful]
// QKV[f][n] = in_b[f] + sum_e Wt[e][f] * X[n][e]        (288 x 16)
// per head h, per s: softmax over t of q[s]k[t], out = attn @ v
// final[n][f] = out_b[f] + sum_h Wo[f][h] * AO[n][h] -> d_out (raw reshape back)
__global__ __launch_bounds__(288) void k_msa(const float* __restrict__ emb,
                                             const float* __restrict__ wt,
                                             const float* __restrict__ in_b,
                                             const float* __restrict__ out_w,
                                             const float* __restrict__ out_b,
                                             float* __restrict__ out) {
    const int bid = blockIdx.x;           // w*1024 + l
    const int w = bid >> 10, l = bid & 1023;
    const int t = threadIdx.x;
    const int base = w * 98304 + l * 96;

    __shared__ float Xs[96][16];          // [e][n]
    __shared__ float QKVs[288][20];       // [f][n], padded rows (80B, 16B-aligned)
    __shared__ float AOs[16][96];         // [n][h]

    // ---- phase 0: load X
    for (int idx = t; idx < 1536; idx += 288) {
        const int n = idx / 96, e = idx % 96;
        Xs[e][n] = emb[(size_t)n * EMB_STRIDE + base + e];
    }
    __syncthreads();

    // ---- phase 1: QKV GEMM, 4n x 4f register tile per thread
    {
        const int nq = t & 3, fq = t >> 2;   // fq in [0,72)
        float acc[4][4];
        const float4 bv = *(const float4*)(in_b + fq * 4);
        const float ba[4] = {bv.x, bv.y, bv.z, bv.w};
#pragma unroll
        for (int fi = 0; fi < 4; ++fi)
#pragma unroll
            for (int ni = 0; ni < 4; ++ni) acc[fi][ni] = ba[fi];

#pragma unroll 4
        for (int e = 0; e < 96; ++e) {
            const float4 xv = *(const float4*)&Xs[e][nq * 4];
            const float4 wv = *(const float4*)(wt + e * 288 + fq * 4);
            const float xa[4] = {xv.x, xv.y, xv.z, xv.w};
            const float wa[4] = {wv.x, wv.y, wv.z, wv.w};
#pragma unroll
            for (int fi = 0; fi < 4; ++fi)
#pragma unroll
                for (int ni = 0; ni < 4; ++ni) acc[fi][ni] += wa[fi] * xa[ni];
        }
#pragma unroll
        for (int fi = 0; fi < 4; ++fi)
            *(float4*)&QKVs[fq * 4 + fi][nq * 4] =
                make_float4(acc[fi][0], acc[fi][1], acc[fi][2], acc[fi][3]);
    }
    __syncthreads();

    // ---- phase 2: attention per (h, s) over the 16 samples
    for (int idx = t; idx < 1536; idx += 288) {
        const int h = idx % 96, s = idx / 96;
        const float q = QKVs[h][s];
        const float4* kr = (const float4*)&QKVs[96 + h][0];
        const float4* vr = (const float4*)&QKVs[192 + h][0];
        float ka[16], va[16], p[16];
        ((float4*)ka)[0] = kr[0]; ((float4*)ka)[1] = kr[1];
        ((float4*)ka)[2] = kr[2]; ((float4*)ka)[3] = kr[3];
        ((float4*)va)[0] = vr[0]; ((float4*)va)[1] = vr[1];
        ((float4*)va)[2] = vr[2]; ((float4*)va)[3] = vr[3];

        float m = -3.402823e38f;
#pragma unroll
        for (int i = 0; i < 16; ++i) { p[i] = q * ka[i]; m = fmaxf(m, p[i]); }
        float sum = 0.f;
#pragma unroll
        for (int i = 0; i < 16; ++i) { p[i] = __expf(p[i] - m); sum += p[i]; }
        float o = 0.f;
#pragma unroll
        for (int i = 0; i < 16; ++i) o += p[i] * va[i];
        AOs[s][h] = o * (1.0f / sum);
    }
    __syncthreads();

    // ---- phase 3: out-proj, write directly to d_out
    for (int idx = t; idx < 1536; idx += 288) {
        const int f = idx % 96, n = idx / 96;
        float acc = out_b[f];
        const float* wr = out_w + f * 96;
        const float* ar = AOs[n];
#pragma unroll
        for (int h = 0; h < 96; h += 4) {
            const float4 wv = *(const float4*)(wr + h);
            const float4 av = *(const float4*)(ar + h);
            acc += wv.x * av.x + wv.y * av.y + wv.z * av.z + wv.w * av.w;
        }
        out[(size_t)n * EMB_STRIDE + base + f] = acc;
    }
}

extern "C" void kernel_launch(void* const* d_in, const int* in_sizes, int n_in,
                              void* d_out, int out_size, void* d_ws, size_t ws_size,
                              hipStream_t stream) {
    const float* x     = (const float*)d_in[0];
    const float* lin_w = (const float*)d_in[1];
    const float* lin_b = (const float*)d_in[2];
    const float* in_w  = (const float*)d_in[3];
    const float* in_b  = (const float*)d_in[4];
    const float* out_w = (const float*)d_in[5];
    const float* out_b = (const float*)d_in[6];
    float* outp = (float*)d_out;

    float* wt  = (float*)d_ws;       // 96*288 = 27648 floats
    float* emb = wt + 32768;         // 16*393216 floats (25.2 MB)

    k_transpose<<<108, 256, 0, stream>>>(in_w, wt);
    k_patch_linear<<<256, 1024, 0, stream>>>(x, lin_w, lin_b, emb);
    k_msa<<<4096, 288, 0, stream>>>(emb, wt, in_b, out_w, out_b, outp);
}

// Round 4
// 150.150 us; speedup vs baseline: 2.8398x; 2.8398x over previous
//
#include <hip/hip_runtime.h>

#define EMB_STRIDE 393216  // 96*64*64 floats per sample

typedef __attribute__((ext_vector_type(8))) short short8;
typedef __attribute__((ext_vector_type(4))) float f32x4;

#define MFMA16 __builtin_amdgcn_mfma_f32_16x16x32_bf16

static __device__ __forceinline__ short bf16h(float v) {
    unsigned u = __builtin_bit_cast(unsigned, v);
    unsigned r = (u + 0x7FFFu + ((u >> 16) & 1u)) >> 16;
    return (short)r;
}
static __device__ __forceinline__ float bf16f(short s) {
    unsigned u = ((unsigned)(unsigned short)s) << 16;
    return __builtin_bit_cast(float, u);
}

// ---------------- Kernel P: pack W (in_proj 288x96, out_proj 96x96) into
// MFMA A-frag order, split hi/lo bf16.
// element i = ((kc*F + f)*4 + g)*8 + j  <->  W[f][kc*32 + g*8 + j]
__global__ __launch_bounds__(256) void k_prep(const float* __restrict__ in_w,
                                              const float* __restrict__ out_w,
                                              short* __restrict__ WH, short* __restrict__ WL2,
                                              short* __restrict__ WOH, short* __restrict__ WOL) {
    int i = blockIdx.x * 256 + threadIdx.x;
    if (i < 27648) {
        int j = i & 7, g = (i >> 3) & 3, rest = i >> 5;
        int f = rest % 288, kc = rest / 288;
        float v = in_w[f * 96 + kc * 32 + g * 8 + j];
        short h = bf16h(v);
        WH[i] = h; WL2[i] = bf16h(v - bf16f(h));
    } else if (i < 27648 + 9216) {
        int i2 = i - 27648;
        int j = i2 & 7, g = (i2 >> 3) & 3, rest = i2 >> 5;
        int f = rest % 96, kc = rest / 96;
        float v = out_w[f * 96 + kc * 32 + g * 8 + j];
        short h = bf16h(v);
        WOH[i2] = h; WOL[i2] = bf16h(v - bf16f(h));
    }
}

// ---------------- Kernel 1: patch merge (RAW reshape semantics) + 48->96 linear
__global__ __launch_bounds__(1024) void k_patch_linear(const float* __restrict__ x,
                                                       const float* __restrict__ lin_w,
                                                       const float* __restrict__ lin_b,
                                                       float* __restrict__ emb) {
    const int bid = blockIdx.x;
    const int n  = bid >> 4;
    const int a  = (bid >> 2) & 3;
    const int eq = bid & 3;
    const int t  = threadIdx.x;

    __shared__ float lw[24 * 48];
    __shared__ float lb[24];
    for (int i = t; i < 24 * 48; i += 1024) lw[i] = lin_w[eq * 24 * 48 + i];
    if (t < 24) lb[t] = lin_b[eq * 24 + t];
    __syncthreads();

    const int b  = t >> 6;
    const int cc = (t >> 4) & 3;
    const int d  = (t >> 2) & 3;
    const int g  = t & 3;
    const int col  = b * 16 + cc * 4 + g;
    const int row0 = a * 4 + d;

    float xv[48];
    const float* xb = x + (size_t)n * 3 * 65536;
#pragma unroll
    for (int c = 0; c < 3; ++c)
#pragma unroll
        for (int j = 0; j < 16; ++j)
            xv[c * 16 + j] = xb[(size_t)(c * 256 + j * 16 + row0) * 256 + col];

    float* ebase = emb + (size_t)n * EMB_STRIDE + a * 1024 + t;
    for (int ei = 0; ei < 24; ++ei) {
        const float* wr = &lw[ei * 48];
        float acc = lb[ei];
#pragma unroll
        for (int k = 0; k < 48; k += 4) {
            acc += xv[k]     * wr[k]     + xv[k + 1] * wr[k + 1]
                 + xv[k + 2] * wr[k + 2] + xv[k + 3] * wr[k + 3];
        }
        ebase[(size_t)(eq * 24 + ei) * 4096] = acc;
    }
}

// ---------------- Kernel 2: fused window-MSA, one wave per (w,l), MFMA bf16x2
__global__ __launch_bounds__(256, 2) void k_msa(
    const float* __restrict__ emb,
    const short* __restrict__ WH, const short* __restrict__ WL2,
    const short* __restrict__ WOH, const short* __restrict__ WOL,
    const float* __restrict__ in_b, const float* __restrict__ out_b,
    float* __restrict__ out) {

    __shared__ float wbuf_all[4][1664];  // per-wave scratch (AO [96][17] then Out [16][104])
    const int wave = threadIdx.x >> 6, lane = threadIdx.x & 63;
    float* wbuf = wbuf_all[wave];
    const int wl = blockIdx.x * 4 + wave;
    const int base = wl * 96;
    const int n = lane & 15, g = lane >> 4;

    // ---- B-frags (X^T) from emb, hi/lo split.  lane: col=n, k = kc*32+g*8+j
    short8 Bh[3], Bl[3];
    const float* xrow = emb + (size_t)n * EMB_STRIDE + base;
#pragma unroll
    for (int kc = 0; kc < 3; ++kc) {
        const float4 v0 = *(const float4*)(xrow + kc * 32 + g * 8);
        const float4 v1 = *(const float4*)(xrow + kc * 32 + g * 8 + 4);
        const float tmp[8] = {v0.x, v0.y, v0.z, v0.w, v1.x, v1.y, v1.z, v1.w};
#pragma unroll
        for (int j = 0; j < 8; ++j) {
            const short h = bf16h(tmp[j]);
            Bh[kc][j] = h;
            Bl[kc][j] = bf16h(tmp[j] - bf16f(h));
        }
    }

    // ---- QKV: C[f][n] = W @ X^T, 18 f-tiles, K=96, bf16x2 (hh + hl + lh)
    f32x4 acc[18];
#pragma unroll
    for (int ft = 0; ft < 18; ++ft) acc[ft] = (f32x4){0.f, 0.f, 0.f, 0.f};
#pragma unroll
    for (int kc = 0; kc < 3; ++kc) {
        const short* wh = WH  + (kc * 288 + n) * 32 + g * 8;
        const short* wl_ = WL2 + (kc * 288 + n) * 32 + g * 8;
#pragma unroll
        for (int ft = 0; ft < 18; ++ft) {
            const short8 ah = *(const short8*)(wh + ft * 512);
            const short8 al = *(const short8*)(wl_ + ft * 512);
            acc[ft] = MFMA16(ah, Bh[kc], acc[ft], 0, 0, 0);
            acc[ft] = MFMA16(ah, Bl[kc], acc[ft], 0, 0, 0);
            acc[ft] = MFMA16(al, Bh[kc], acc[ft], 0, 0, 0);
        }
    }
    // bias (C row f = ft*16 + g*4 + reg)
#pragma unroll
    for (int ft = 0; ft < 18; ++ft) {
        const float4 bv = *(const float4*)(in_b + ft * 16 + g * 4);
        acc[ft][0] += bv.x; acc[ft][1] += bv.y; acc[ft][2] += bv.z; acc[ft][3] += bv.w;
    }

    // ---- attention: head h = t*16 + g*4 + r2 lives in this 16-lane group
    // lane holds q[h][n], k[h][n], v[h][n]; softmax over the 16 samples.
    // broadcast within group: src lane = (lane & 48) | tt  (dynamic -> ds_bpermute)
    const int gbase = lane & 48;
#pragma unroll
    for (int t = 0; t < 6; ++t) {
#pragma unroll
        for (int r2 = 0; r2 < 4; ++r2) {
            const float q = acc[t][r2];
            const float kv = acc[6 + t][r2];
            const float vv = acc[12 + t][r2];
            float p[16], vb[16];
#pragma unroll
            for (int tt = 0; tt < 16; ++tt) {
                p[tt]  = q * __shfl(kv, gbase | tt, 64);
                vb[tt] = __shfl(vv, gbase | tt, 64);
            }
            float m = p[0];
#pragma unroll
            for (int tt = 1; tt < 16; ++tt) m = fmaxf(m, p[tt]);
            float s = 0.f, o = 0.f;
#pragma unroll
            for (int tt = 0; tt < 16; ++tt) {
                const float e = __expf(p[tt] - m);
                s += e; o += e * vb[tt];
            }
            wbuf[(t * 16 + g * 4 + r2) * 17 + n] = o / s;  // AO[h][n]
        }
    }

    // ---- out-proj: out[f2][n] = Wo @ AO^T, 6 f-tiles, K=96, bf16x2
    f32x4 acc2[6];
#pragma unroll
    for (int ft = 0; ft < 6; ++ft) acc2[ft] = (f32x4){0.f, 0.f, 0.f, 0.f};
#pragma unroll
    for (int kc = 0; kc < 3; ++kc) {
        short8 bh2, bl2;
#pragma unroll
        for (int j = 0; j < 8; ++j) {
            const float a = wbuf[(kc * 32 + g * 8 + j) * 17 + n];
            const short h = bf16h(a);
            bh2[j] = h; bl2[j] = bf16h(a - bf16f(h));
        }
        const short* wh = WOH + (kc * 96 + n) * 32 + g * 8;
        const short* wl_ = WOL + (kc * 96 + n) * 32 + g * 8;
#pragma unroll
        for (int ft = 0; ft < 6; ++ft) {
            const short8 ah = *(const short8*)(wh + ft * 512);
            const short8 al = *(const short8*)(wl_ + ft * 512);
            acc2[ft] = MFMA16(ah, bh2, acc2[ft], 0, 0, 0);
            acc2[ft] = MFMA16(ah, bl2, acc2[ft], 0, 0, 0);
            acc2[ft] = MFMA16(al, bh2, acc2[ft], 0, 0, 0);
        }
    }
    // bias + transpose to [n][f2] rows (104-float rows, 16B aligned)
#pragma unroll
    for (int ft = 0; ft < 6; ++ft) {
        const float4 ob = *(const float4*)(out_b + ft * 16 + g * 4);
        wbuf[n * 104 + ft * 16 + g * 4 + 0] = acc2[ft][0] + ob.x;
        wbuf[n * 104 + ft * 16 + g * 4 + 1] = acc2[ft][1] + ob.y;
        wbuf[n * 104 + ft * 16 + g * 4 + 2] = acc2[ft][2] + ob.z;
        wbuf[n * 104 + ft * 16 + g * 4 + 3] = acc2[ft][3] + ob.w;
    }

    // ---- coalesced store: lane -> (row = lane>>2, quarter = lane&3)
    {
        const int row = lane >> 2, q4 = lane & 3;
        float* orow = out + (size_t)row * EMB_STRIDE + base;
#pragma unroll
        for (int mi = 0; mi < 6; ++mi) {
            const int fo = (q4 * 6 + mi) * 4;
            const float4 v = *(const float4*)&wbuf[row * 104 + fo];
            *(float4*)(orow + fo) = v;
        }
    }
}

extern "C" void kernel_launch(void* const* d_in, const int* in_sizes, int n_in,
                              void* d_out, int out_size, void* d_ws, size_t ws_size,
                              hipStream_t stream) {
    const float* x     = (const float*)d_in[0];
    const float* lin_w = (const float*)d_in[1];
    const float* lin_b = (const float*)d_in[2];
    const float* in_w  = (const float*)d_in[3];
    const float* in_b  = (const float*)d_in[4];
    const float* out_w = (const float*)d_in[5];
    const float* out_b = (const float*)d_in[6];
    float* outp = (float*)d_out;

    float* emb = (float*)d_ws;                              // 25165824 B
    short* WH  = (short*)((char*)d_ws + 25165824);          // 27648 shorts
    short* WL2 = WH + 32768;
    short* WOH = WH + 65536;                                // 9216 shorts
    short* WOL = WH + 81920;

    k_prep<<<144, 256, 0, stream>>>(in_w, out_w, WH, WL2, WOH, WOL);
    k_patch_linear<<<256, 1024, 0, stream>>>(x, lin_w, lin_b, emb);
    k_msa<<<1024, 256, 0, stream>>>(emb, WH, WL2, WOH, WOL, in_b, out_b, outp);
}

// Round 5
// 111.129 us; speedup vs baseline: 3.8370x; 1.3511x over previous
//
#include <hip/hip_runtime.h>

#define EMB_STRIDE 393216  // 96*64*64 floats per sample

typedef __attribute__((ext_vector_type(8))) short short8;
typedef __attribute__((ext_vector_type(4))) float f32x4;

#define MFMA16 __builtin_amdgcn_mfma_f32_16x16x32_bf16

static __device__ __forceinline__ short bf16h(float v) {
    unsigned u = __builtin_bit_cast(unsigned, v);
    unsigned r = (u + 0x7FFFu + ((u >> 16) & 1u)) >> 16;
    return (short)r;
}
static __device__ __forceinline__ float bf16f(short s) {
    unsigned u = ((unsigned)(unsigned short)s) << 16;
    return __builtin_bit_cast(float, u);
}

// ---------------- Kernel 1: blocks [0,256): patch merge (RAW reshape) + linear
//                  block 256: pack in_proj/out_proj into MFMA A-frag hi/lo bf16
__global__ __launch_bounds__(1024) void k_patch_prep(
    const float* __restrict__ x, const float* __restrict__ lin_w,
    const float* __restrict__ lin_b, const float* __restrict__ in_w,
    const float* __restrict__ out_w, float* __restrict__ emb,
    short* __restrict__ WH, short* __restrict__ WL2,
    short* __restrict__ WOH, short* __restrict__ WOL) {
    const int bid = blockIdx.x;
    const int t = threadIdx.x;

    if (bid >= 256) {
        // ---- weight prep: element i = ((kc*F + f)*4 + g)*8 + j <-> W[f][kc*32+g*8+j]
        for (int i = t; i < 27648; i += 1024) {
            int j = i & 7, g = (i >> 3) & 3, rest = i >> 5;
            int f = rest % 288, kc = rest / 288;
            float v = in_w[f * 96 + kc * 32 + g * 8 + j];
            short h = bf16h(v);
            WH[i] = h; WL2[i] = bf16h(v - bf16f(h));
        }
        for (int i = t; i < 9216; i += 1024) {
            int j = i & 7, g = (i >> 3) & 3, rest = i >> 5;
            int f = rest % 96, kc = rest / 96;
            float v = out_w[f * 96 + kc * 32 + g * 8 + j];
            short h = bf16h(v);
            WOH[i] = h; WOL[i] = bf16h(v - bf16f(h));
        }
        return;
    }

    const int n  = bid >> 4;
    const int a  = (bid >> 2) & 3;
    const int eq = bid & 3;

    __shared__ float lw[24 * 48];
    __shared__ float lb[24];
    for (int i = t; i < 24 * 48; i += 1024) lw[i] = lin_w[eq * 24 * 48 + i];
    if (t < 24) lb[t] = lin_b[eq * 24 + t];
    __syncthreads();

    const int b  = t >> 6;
    const int cc = (t >> 4) & 3;
    const int d  = (t >> 2) & 3;
    const int g  = t & 3;
    const int col  = b * 16 + cc * 4 + g;
    const int row0 = a * 4 + d;

    float xv[48];
    const float* xb = x + (size_t)n * 3 * 65536;
#pragma unroll
    for (int c = 0; c < 3; ++c)
#pragma unroll
        for (int j = 0; j < 16; ++j)
            xv[c * 16 + j] = xb[(size_t)(c * 256 + j * 16 + row0) * 256 + col];

    float* ebase = emb + (size_t)n * EMB_STRIDE + a * 1024 + t;
    for (int ei = 0; ei < 24; ++ei) {
        const float* wr = &lw[ei * 48];
        float acc = lb[ei];
#pragma unroll
        for (int k = 0; k < 48; k += 4) {
            acc += xv[k]     * wr[k]     + xv[k + 1] * wr[k + 1]
                 + xv[k + 2] * wr[k + 2] + xv[k + 3] * wr[k + 3];
        }
        ebase[(size_t)(eq * 24 + ei) * 4096] = acc;
    }
}

// ---------------- Kernel 2: fused window-MSA, TWO half-waves per (w,l)
// half-wave owns 48 heads: QKV ft = cat*6 + half*3 + c (cat 0=q,1=k,2=v; c 0..2)
__global__ __launch_bounds__(256, 4) void k_msa(
    const float* __restrict__ emb,
    const short* __restrict__ WH, const short* __restrict__ WL2,
    const short* __restrict__ WOH, const short* __restrict__ WOL,
    const float* __restrict__ in_b, const float* __restrict__ out_b,
    float* __restrict__ out) {

    __shared__ float ao_s[2][96 * 17];   // per-wl AO[h][n] (stride 17)
    __shared__ float ob_s[2][16 * 104];  // per-wl out rows [n][f] (stride 104)

    const int tid = threadIdx.x;
    const int wave = tid >> 6, lane = tid & 63;
    const int wl_local = wave >> 1, half = wave & 1;
    const int wl = blockIdx.x * 2 + wl_local;
    const int base = wl * 96;
    const int n = lane & 15, g = lane >> 4;
    float* AO = ao_s[wl_local];
    float* OB = ob_s[wl_local];

    // ---- B-frags (X^T) from emb, hi/lo split.  lane: col=n, k = kc*32+g*8+j
    short8 Bh[3], Bl[3];
    const float* xrow = emb + (size_t)n * EMB_STRIDE + base;
#pragma unroll
    for (int kc = 0; kc < 3; ++kc) {
        const float4 v0 = *(const float4*)(xrow + kc * 32 + g * 8);
        const float4 v1 = *(const float4*)(xrow + kc * 32 + g * 8 + 4);
        const float tmp[8] = {v0.x, v0.y, v0.z, v0.w, v1.x, v1.y, v1.z, v1.w};
#pragma unroll
        for (int j = 0; j < 8; ++j) {
            const short h = bf16h(tmp[j]);
            Bh[kc][j] = h;
            Bl[kc][j] = bf16h(tmp[j] - bf16f(h));
        }
    }

    // ---- QKV: 9 f-tiles (this half's q,k,v), K=96, bf16x2 (hh+hl+lh)
    f32x4 acc[9];
#pragma unroll
    for (int a = 0; a < 9; ++a) acc[a] = (f32x4){0.f, 0.f, 0.f, 0.f};
    const int hoff = half * 1536;  // (half*3)*512
#pragma unroll
    for (int kc = 0; kc < 3; ++kc) {
        const short* whp = WH  + kc * 9216 + n * 32 + g * 8 + hoff;
        const short* wlp = WL2 + kc * 9216 + n * 32 + g * 8 + hoff;
#pragma unroll
        for (int a = 0; a < 9; ++a) {
            const int fto = ((a / 3) * 6 + (a % 3)) * 512;  // + half*1536 folded
            const short8 ah = *(const short8*)(whp + fto);
            const short8 al = *(const short8*)(wlp + fto);
            acc[a] = MFMA16(ah, Bh[kc], acc[a], 0, 0, 0);
            acc[a] = MFMA16(ah, Bl[kc], acc[a], 0, 0, 0);
            acc[a] = MFMA16(al, Bh[kc], acc[a], 0, 0, 0);
        }
    }
    // bias: f = (cat*6 + half*3 + c)*16 + g*4 + r
#pragma unroll
    for (int a = 0; a < 9; ++a) {
        const float4 bv = *(const float4*)(in_b + ((a / 3) * 6 + (a % 3)) * 16 + half * 48 + g * 4);
        acc[a][0] += bv.x; acc[a][1] += bv.y; acc[a][2] += bv.z; acc[a][3] += bv.w;
    }

    // ---- attention: 12 head-regs; head h = half*48 + c*16 + g*4 + r2; s = n
    const int gbase = lane & 48;
#pragma unroll
    for (int c = 0; c < 3; ++c) {
#pragma unroll
        for (int r2 = 0; r2 < 4; ++r2) {
            const float q  = acc[c][r2];
            const float kv = acc[3 + c][r2];
            const float vv = acc[6 + c][r2];
            float p[16], vb[16];
#pragma unroll
            for (int tt = 0; tt < 16; ++tt) {
                p[tt]  = q * __shfl(kv, gbase | tt, 64);
                vb[tt] = __shfl(vv, gbase | tt, 64);
            }
            // tree max (depth 4)
            float m01 = fmaxf(p[0], p[1]),   m23 = fmaxf(p[2], p[3]);
            float m45 = fmaxf(p[4], p[5]),   m67 = fmaxf(p[6], p[7]);
            float m89 = fmaxf(p[8], p[9]),   mab = fmaxf(p[10], p[11]);
            float mcd = fmaxf(p[12], p[13]), mef = fmaxf(p[14], p[15]);
            float m0123 = fmaxf(m01, m23), m4567 = fmaxf(m45, m67);
            float m89ab = fmaxf(m89, mab), mcdef = fmaxf(mcd, mef);
            const float m = fmaxf(fmaxf(m0123, m4567), fmaxf(m89ab, mcdef));
            float e[16];
#pragma unroll
            for (int tt = 0; tt < 16; ++tt) e[tt] = __expf(p[tt] - m);
            // 4-way partial sums (depth ~5)
            float s0 = e[0] + e[4], s1 = e[1] + e[5], s2 = e[2] + e[6], s3 = e[3] + e[7];
            s0 += e[8] + e[12]; s1 += e[9] + e[13]; s2 += e[10] + e[14]; s3 += e[11] + e[15];
            const float s = (s0 + s1) + (s2 + s3);
            float o0 = e[0] * vb[0], o1 = e[1] * vb[1], o2 = e[2] * vb[2], o3 = e[3] * vb[3];
#pragma unroll
            for (int tt = 4; tt < 16; tt += 4) {
                o0 += e[tt] * vb[tt]; o1 += e[tt + 1] * vb[tt + 1];
                o2 += e[tt + 2] * vb[tt + 2]; o3 += e[tt + 3] * vb[tt + 3];
            }
            const float o = (o0 + o1) + (o2 + o3);
            AO[(half * 48 + c * 16 + g * 4 + r2) * 17 + n] = o * __builtin_amdgcn_rcpf(s);
        }
    }
    __syncthreads();

    // ---- out-proj: 3 f-tiles (this half's 48 output features), K=96
    f32x4 acc2[3];
#pragma unroll
    for (int c2 = 0; c2 < 3; ++c2) acc2[c2] = (f32x4){0.f, 0.f, 0.f, 0.f};
#pragma unroll
    for (int kc = 0; kc < 3; ++kc) {
        short8 bh2, bl2;
#pragma unroll
        for (int j = 0; j < 8; ++j) {
            const float a = AO[(kc * 32 + g * 8 + j) * 17 + n];
            const short h = bf16h(a);
            bh2[j] = h; bl2[j] = bf16h(a - bf16f(h));
        }
        const short* whp = WOH + kc * 3072 + n * 32 + g * 8 + hoff;
        const short* wlp = WOL + kc * 3072 + n * 32 + g * 8 + hoff;
#pragma unroll
        for (int c2 = 0; c2 < 3; ++c2) {
            const short8 ah = *(const short8*)(whp + c2 * 512);
            const short8 al = *(const short8*)(wlp + c2 * 512);
            acc2[c2] = MFMA16(ah, bh2, acc2[c2], 0, 0, 0);
            acc2[c2] = MFMA16(ah, bl2, acc2[c2], 0, 0, 0);
            acc2[c2] = MFMA16(al, bh2, acc2[c2], 0, 0, 0);
        }
    }
    // bias + stage rows [n][f] (this half's f-columns only)
#pragma unroll
    for (int c2 = 0; c2 < 3; ++c2) {
        const int fb = half * 48 + c2 * 16 + g * 4;
        const float4 ob = *(const float4*)(out_b + fb);
        OB[n * 104 + fb + 0] = acc2[c2][0] + ob.x;
        OB[n * 104 + fb + 1] = acc2[c2][1] + ob.y;
        OB[n * 104 + fb + 2] = acc2[c2][2] + ob.z;
        OB[n * 104 + fb + 3] = acc2[c2][3] + ob.w;
    }

    // ---- coalesced store of this half's 48 f-columns, all 16 rows
    {
        const int row = lane >> 2, q4 = lane & 3;
        float* orow = out + (size_t)row * EMB_STRIDE + base + half * 48;
        const float* srow = &OB[row * 104 + half * 48];
#pragma unroll
        for (int mi = 0; mi < 3; ++mi) {
            const int fo = q4 * 12 + mi * 4;
            *(float4*)(orow + fo) = *(const float4*)(srow + fo);
        }
    }
}

extern "C" void kernel_launch(void* const* d_in, const int* in_sizes, int n_in,
                              void* d_out, int out_size, void* d_ws, size_t ws_size,
                              hipStream_t stream) {
    const float* x     = (const float*)d_in[0];
    const float* lin_w = (const float*)d_in[1];
    const float* lin_b = (const float*)d_in[2];
    const float* in_w  = (const float*)d_in[3];
    const float* in_b  = (const float*)d_in[4];
    const float* out_w = (const float*)d_in[5];
    const float* out_b = (const float*)d_in[6];
    float* outp = (float*)d_out;

    float* emb = (float*)d_ws;                              // 25165824 B
    short* WH  = (short*)((char*)d_ws + 25165824);          // 27648 shorts
    short* WL2 = WH + 32768;
    short* WOH = WH + 65536;                                // 9216 shorts
    short* WOL = WH + 81920;

    k_patch_prep<<<257, 1024, 0, stream>>>(x, lin_w, lin_b, in_w, out_w,
                                           emb, WH, WL2, WOH, WOL);
    k_msa<<<2048, 256, 0, stream>>>(emb, WH, WL2, WOH, WOL, in_b, out_b, outp);
}